// Round 8
// baseline (216.191 us; speedup 1.0000x reference)
//
#include <hip/hip_runtime.h>

typedef _Float16 half8  __attribute__((ext_vector_type(8)));
typedef __fp16   half2v __attribute__((ext_vector_type(2)));   // cvt_pkrtz return type
typedef float    f32x4  __attribute__((ext_vector_type(4)));
typedef float    f32x2  __attribute__((ext_vector_type(2)));

#define L2E 1.44269504088896340736f
#define MFMA(a, b, c) __builtin_amdgcn_mfma_f32_16x16x32_f16((a), (b), (c), 0, 0, 0)

// Row-permuted + pre-scaled weights: D-fragment of gates^T = Wc·h^T lands
// i,f,g,o for (agent=col, j=8q+i) in-lane; activation output is directly the
// next step's B-fragment. slot s: gi=s>>5, hf=(s>>4)&1, q=(s>>2)&3, r=s&3
//   -> orig gate row o = gi*32 + 8q + 4hf + r.
// ws float layout:
//   0    : Wcs [128][32]  permuted, scaled folded recurrent weights
//   4096 : Whhs[128][32]  permuted, scaled W_hh (step 0)
//   8192 : W00s[128]      permuted, scaled lp0 rank-1 column
//   8320 : W01s[128]      permuted, scaled lp1 rank-1 column
//   8448 : bg2s[128]      permuted, scaled steady-state gate bias
//   8576 : b0s [128]      permuted, scaled step-0 gate bias
__global__ void precompute_kernel(const float* __restrict__ W_se,
                                  const float* __restrict__ b_se,
                                  const float* __restrict__ W_ih,
                                  const float* __restrict__ b_ih,
                                  const float* __restrict__ W_hh,
                                  const float* __restrict__ b_hh,
                                  const float* __restrict__ W_hp,
                                  const float* __restrict__ b_hp,
                                  float* __restrict__ ws) {
    int s = threadIdx.x;
    if (s >= 128) return;
    int gi = s >> 5, hf = (s >> 4) & 1, q = (s >> 2) & 3, r = s & 3;
    int o  = gi * 32 + 8 * q + 4 * hf + r;          // original gate row
    float w0 = 0.f, w1 = 0.f, bse = 0.f;
    for (int e = 0; e < 32; ++e) {
        float wi = W_ih[o * 32 + e];
        w0  += W_se[e * 2 + 0] * wi;
        w1  += W_se[e * 2 + 1] * wi;
        bse += b_se[e] * wi;
    }
    // i,f,o rows scaled by -log2e (sigmoid via exp2); g rows by 2*log2e (tanh)
    float sc = (gi == 2) ? 2.0f * L2E : -L2E;
    for (int k = 0; k < 32; ++k) {
        float whh = W_hh[o * 32 + k];
        ws[s * 32 + k]        = sc * (whh + W_hp[k] * w0 + W_hp[32 + k] * w1);
        ws[4096 + s * 32 + k] = sc * whh;
    }
    float bg = b_ih[o] + b_hh[o] + bse;
    ws[8192 + s] = sc * w0;
    ws[8320 + s] = sc * w1;
    ws[8448 + s] = sc * (bg + b_hp[0] * w0 + b_hp[1] * w1);
    ws[8576 + s] = sc * bg;
}

// exact hi/lo f16 split of 8 floats
__device__ __forceinline__ void split8(const float* v, half8& hi, half8& lo) {
    #pragma unroll
    for (int p = 0; p < 4; ++p) {
        half2v hp = __builtin_amdgcn_cvt_pkrtz(v[2 * p], v[2 * p + 1]);
        hi[2 * p] = hp.x; hi[2 * p + 1] = hp.y;
        float l0 = v[2 * p]     - (float)hp.x;
        float l1 = v[2 * p + 1] - (float)hp.y;
        half2v lp2 = __builtin_amdgcn_cvt_pkrtz(l0, l1);
        lo[2 * p] = lp2.x; lo[2 * p + 1] = lp2.y;
    }
}

// Dual-tile: each wave owns 32 agents (two 16-agent MFMA tiles sharing the
// weight fragments) -> 2x ILP per wave at ~same weight-register cost.
// 4 waves/block, 128 agents/block. No LDS, no syncs.
__global__ __launch_bounds__(256, 3) void lstm_kernel(
        const float* __restrict__ lp,    // last_pos_rel (B,2)
        const float* __restrict__ h0g,   // hidden_state (1,B,32)
        const float* __restrict__ sp,    // start_pos (B,2)
        const float* __restrict__ Whp,   // (2,32)
        const float* __restrict__ bhp,   // (2)
        const float* __restrict__ ws,
        const int*   __restrict__ seqp,
        float* __restrict__ out, int Bn) {
    const int lane  = threadIdx.x & 63;
    const int col   = lane & 15;         // agent within tile
    const int q     = lane >> 4;
    const int baseA = (blockIdx.x * 8 + (threadIdx.x >> 6) * 2) * 16;
    const int baseB = baseA + 16;
    if (baseA >= Bn) return;
    const int T = seqp[0];

    const float* Wcs  = ws;
    const float* Whhs = ws + 4096;
    const float* W00s = ws + 8192;
    const float* W01s = ws + 8320;
    const float* bg2q = ws + 8448 + 4 * q;   // per-lane bias base
    const float* b0sq = ws + 8576 + 4 * q;

    // persistent shared A-fragments: folded weights + pos head (f16 hi)
    half8 wh[8];
    #pragma unroll
    for (int t8 = 0; t8 < 8; ++t8) {
        const float* p = Wcs + (size_t)(t8 * 16 + col) * 32 + 8 * q;
        #pragma unroll
        for (int pp = 0; pp < 4; ++pp) {
            half2v h2 = __builtin_amdgcn_cvt_pkrtz(p[2 * pp], p[2 * pp + 1]);
            wh[t8][2 * pp] = h2.x; wh[t8][2 * pp + 1] = h2.y;
        }
    }
    half8 ph;
    #pragma unroll
    for (int pp = 0; pp < 4; ++pp) {
        float v0 = (col < 2) ? Whp[col * 32 + 8 * q + 2 * pp]     : 0.f;
        float v1 = (col < 2) ? Whp[col * 32 + 8 * q + 2 * pp + 1] : 0.f;
        half2v h2 = __builtin_amdgcn_cvt_pkrtz(v0, v1);
        ph[2 * pp] = h2.x; ph[2 * pp + 1] = h2.y;
    }
    const float pb0 = (q == 0) ? bhp[0] : 0.f;
    const float pb1 = (q == 0) ? bhp[1] : 0.f;

    // ---- step 0 (one-time, full hi/lo precision on fp32 inputs) ----
    f32x4 accgA[8], accgB[8];
    {
        half8 bhA0, blA0, bhB0, blB0;
        {
            float v[8];
            const float* pa = h0g + (size_t)(baseA + col) * 32 + 8 * q;
            #pragma unroll
            for (int i = 0; i < 8; ++i) v[i] = pa[i];
            split8(v, bhA0, blA0);
            const float* pb = h0g + (size_t)(baseB + col) * 32 + 8 * q;
            #pragma unroll
            for (int i = 0; i < 8; ++i) v[i] = pb[i];
            split8(v, bhB0, blB0);
        }
        half8 lphA, lplA, lphB, lplB;
        #pragma unroll
        for (int i = 0; i < 8; ++i) {
            lphA[i] = (_Float16)0.f; lplA[i] = (_Float16)0.f;
            lphB[i] = (_Float16)0.f; lplB[i] = (_Float16)0.f;
        }
        if (q == 0) {
            float a0 = lp[(size_t)(baseA + col) * 2 + 0];
            float a1 = lp[(size_t)(baseA + col) * 2 + 1];
            half2v x = __builtin_amdgcn_cvt_pkrtz(a0, a1);
            lphA[0] = x.x; lphA[1] = x.y;
            half2v y = __builtin_amdgcn_cvt_pkrtz(a0 - (float)x.x, a1 - (float)x.y);
            lplA[0] = y.x; lplA[1] = y.y;
            float b0v = lp[(size_t)(baseB + col) * 2 + 0];
            float b1v = lp[(size_t)(baseB + col) * 2 + 1];
            half2v xb = __builtin_amdgcn_cvt_pkrtz(b0v, b1v);
            lphB[0] = xb.x; lphB[1] = xb.y;
            half2v yb = __builtin_amdgcn_cvt_pkrtz(b0v - (float)xb.x, b1v - (float)xb.y);
            lplB[0] = yb.x; lplB[1] = yb.y;
        }
        #pragma unroll
        for (int t8 = 0; t8 < 8; ++t8) {
            f32x4 bias0 = *(const f32x4*)(b0sq + t8 * 16);
            half8 ah;                    // transient Whh fragment, shared A/B
            {
                const float* p = Whhs + (size_t)(t8 * 16 + col) * 32 + 8 * q;
                #pragma unroll
                for (int pp = 0; pp < 4; ++pp) {
                    half2v h2 = __builtin_amdgcn_cvt_pkrtz(p[2 * pp], p[2 * pp + 1]);
                    ah[2 * pp] = h2.x; ah[2 * pp + 1] = h2.y;
                }
            }
            half8 ch;                    // lp rank-2 fragment (k=0,1)
            #pragma unroll
            for (int i = 0; i < 8; ++i) ch[i] = (_Float16)0.f;
            if (q == 0) {
                half2v y = __builtin_amdgcn_cvt_pkrtz(W00s[t8 * 16 + col],
                                                      W01s[t8 * 16 + col]);
                ch[0] = y.x; ch[1] = y.y;
            }
            f32x4 aA = bias0, aB = bias0;
            aA = MFMA(ah, bhA0, aA); aA = MFMA(ah, blA0, aA);
            aA = MFMA(ch, lphA, aA); aA = MFMA(ch, lplA, aA);
            aB = MFMA(ah, bhB0, aB); aB = MFMA(ah, blB0, aB);
            aB = MFMA(ch, lphB, aB); aB = MFMA(ch, lplB, aB);
            accgA[t8] = aA; accgB[t8] = aB;
        }
    }

    // per-lane recurrent state
    f32x2 c2A[4], c2B[4];
    #pragma unroll
    for (int i = 0; i < 4; ++i) { c2A[i] = (f32x2)0.f; c2B[i] = (f32x2)0.f; }
    float runA0 = 0.f, runA1 = 0.f, runB0 = 0.f, runB1 = 0.f;
    if (q == 0) {
        runA0 = sp[(size_t)(baseA + col) * 2 + 0];
        runA1 = sp[(size_t)(baseA + col) * 2 + 1];
        runB0 = sp[(size_t)(baseB + col) * 2 + 0];
        runB1 = sp[(size_t)(baseB + col) * 2 + 1];
    }

    half8 bhA, bhB;                      // h as f16 B-fragment (persists to epilogue)

    // activation for one packet of 2 elements -> writes 2 f16 into bh
    auto act2 = [&](f32x4* accg, f32x2* c2, half8& bh, int hf, int rp) {
        const int idx = 2 * hf + rp;
        f32x2 gI, gF, gG, gO;
        gI.x = accg[0 + hf][2 * rp]; gI.y = accg[0 + hf][2 * rp + 1];
        gF.x = accg[2 + hf][2 * rp]; gF.y = accg[2 + hf][2 * rp + 1];
        gG.x = accg[4 + hf][2 * rp]; gG.y = accg[4 + hf][2 * rp + 1];
        gO.x = accg[6 + hf][2 * rp]; gO.y = accg[6 + hf][2 * rp + 1];
        f32x2 ei, ef, eg, eo;
        ei.x = __builtin_amdgcn_exp2f(gI.x); ei.y = __builtin_amdgcn_exp2f(gI.y);
        ef.x = __builtin_amdgcn_exp2f(gF.x); ef.y = __builtin_amdgcn_exp2f(gF.y);
        eg.x = __builtin_amdgcn_exp2f(gG.x); eg.y = __builtin_amdgcn_exp2f(gG.y);
        eo.x = __builtin_amdgcn_exp2f(gO.x); eo.y = __builtin_amdgcn_exp2f(gO.y);
        f32x2 Df = ef + 1.f;
        f32x2 P  = (ei + 1.f) * (eg + 1.f);
        f32x2 PD = P * Df;
        f32x2 R;
        R.x = __builtin_amdgcn_rcpf(PD.x); R.y = __builtin_amdgcn_rcpf(PD.y);
        f32x2 cn = ((eg - 1.f) * Df + c2[idx] * P) * R;
        c2[idx] = cn;
        f32x2 arg = cn * (2.f * L2E);
        f32x2 ec;
        ec.x = __builtin_amdgcn_exp2f(arg.x); ec.y = __builtin_amdgcn_exp2f(arg.y);
        f32x2 DDo = (ec + 1.f) * (eo + 1.f);
        f32x2 Rs;
        Rs.x = __builtin_amdgcn_rcpf(DDo.x); Rs.y = __builtin_amdgcn_rcpf(DDo.y);
        f32x2 h2 = (ec - 1.f) * Rs;
        half2v hp = __builtin_amdgcn_cvt_pkrtz(h2.x, h2.y);
        bh[2 * idx] = hp.x; bh[2 * idx + 1] = hp.y;
    };

    #pragma unroll 1
    for (int n = 0; n < T; ++n) {
        // ---- activations, tiles interleaved for ILP ----
        #pragma unroll
        for (int hf = 0; hf < 2; ++hf) {
            #pragma unroll
            for (int rp = 0; rp < 2; ++rp) {
                act2(accgA, c2A, bhA, hf, rp);
                act2(accgB, c2B, bhB, hf, rp);
            }
        }

        // ---- pos heads ----
        f32x4 apA, apB;
        apA[0] = pb0; apA[1] = pb1; apA[2] = 0.f; apA[3] = 0.f;
        apB = apA;
        apA = MFMA(ph, bhA, apA);
        apB = MFMA(ph, bhB, apB);

        // ---- gates_{n+1}^T = Wc_perm·h^T + bg2 (bias loaded once, used 2x) ----
        #pragma unroll
        for (int t8 = 0; t8 < 8; ++t8) {
            f32x4 bt = *(const f32x4*)(bg2q + t8 * 16);   // L1-hot, 16 B
            accgA[t8] = MFMA(wh[t8], bhA, bt);
            accgB[t8] = MFMA(wh[t8], bhB, bt);
        }

        // ---- cumsum + coalesced float2 stores (lanes 0..15) ----
        if (q == 0) {
            runA0 += apA[0]; runA1 += apA[1];
            runB0 += apB[0]; runB1 += apB[1];
            float2 wA; wA.x = runA0; wA.y = runA1;
            float2 wB; wB.x = runB0; wB.y = runB1;
            *(float2*)(out + 2 * ((size_t)n * Bn + baseA + col)) = wA;
            *(float2*)(out + 2 * ((size_t)n * Bn + baseB + col)) = wB;
        }
    }

    // ---- final hidden state from the f16 fragments (error ~2.4e-4) ----
    {
        float* pa = out + (size_t)T * Bn * 2 + (size_t)(baseA + col) * 32 + 8 * q;
        float* pb = out + (size_t)T * Bn * 2 + (size_t)(baseB + col) * 32 + 8 * q;
        float4 v0, v1;
        v0.x = (float)bhA[0]; v0.y = (float)bhA[1]; v0.z = (float)bhA[2]; v0.w = (float)bhA[3];
        v1.x = (float)bhA[4]; v1.y = (float)bhA[5]; v1.z = (float)bhA[6]; v1.w = (float)bhA[7];
        *(float4*)(pa)     = v0;
        *(float4*)(pa + 4) = v1;
        v0.x = (float)bhB[0]; v0.y = (float)bhB[1]; v0.z = (float)bhB[2]; v0.w = (float)bhB[3];
        v1.x = (float)bhB[4]; v1.y = (float)bhB[5]; v1.z = (float)bhB[6]; v1.w = (float)bhB[7];
        *(float4*)(pb)     = v0;
        *(float4*)(pb + 4) = v1;
    }
}

extern "C" void kernel_launch(void* const* d_in, const int* in_sizes, int n_in,
                              void* d_out, int out_size, void* d_ws, size_t ws_size,
                              hipStream_t stream) {
    const float* last_pos_rel = (const float*)d_in[0];
    const float* hidden_state = (const float*)d_in[1];
    const float* start_pos    = (const float*)d_in[2];
    const float* W_se         = (const float*)d_in[3];
    const float* b_se         = (const float*)d_in[4];
    const float* W_ih         = (const float*)d_in[5];
    const float* b_ih         = (const float*)d_in[6];
    const float* W_hh         = (const float*)d_in[7];
    const float* b_hh         = (const float*)d_in[8];
    const float* W_hp         = (const float*)d_in[9];
    const float* b_hp         = (const float*)d_in[10];
    const int*   seq_len      = (const int*)d_in[11];

    float* out = (float*)d_out;
    float* ws  = (float*)d_ws;

    const int Bn = in_sizes[0] / 2;

    hipLaunchKernelGGL(precompute_kernel, dim3(1), dim3(128), 0, stream,
                       W_se, b_se, W_ih, b_ih, W_hh, b_hh, W_hp, b_hp, ws);

    const int ntiles = (Bn + 15) / 16;        // 16-agent tiles
    const int nblk   = (ntiles + 7) / 8;      // 8 tiles (128 agents) per block
    hipLaunchKernelGGL(lstm_kernel, dim3(nblk), dim3(256), 0, stream,
                       last_pos_rel, hidden_state, start_pos, W_hp, b_hp,
                       ws, seq_len, out, Bn);
}

// Round 9
// 212.942 us; speedup vs baseline: 1.0153x; 1.0153x over previous
//
#include <hip/hip_runtime.h>

typedef _Float16 half8  __attribute__((ext_vector_type(8)));
typedef __fp16   half2v __attribute__((ext_vector_type(2)));   // cvt_pkrtz return type
typedef float    f32x4  __attribute__((ext_vector_type(4)));
typedef float    f32x2  __attribute__((ext_vector_type(2)));

#define L2E 1.44269504088896340736f
#define MFMA(a, b, c) __builtin_amdgcn_mfma_f32_16x16x32_f16((a), (b), (c), 0, 0, 0)

// Row-permuted + pre-scaled weights: D-fragment of gates^T = Wc·h^T lands
// i,f,g,o for (agent=col, j=8q+i) in-lane; activation output is directly the
// next step's B-fragment. slot s: gi=s>>5, hf=(s>>4)&1, q=(s>>2)&3, r=s&3
//   -> orig gate row o = gi*32 + 8q + 4hf + r.
// ws float layout:
//   0    : Wcs [128][32]  permuted, scaled folded recurrent weights
//   4096 : Whhs[128][32]  permuted, scaled W_hh (step 0)
//   8192 : W00s[128]      permuted, scaled lp0 rank-1 column
//   8320 : W01s[128]      permuted, scaled lp1 rank-1 column
//   8448 : bg2s[128]      permuted, scaled steady-state gate bias
//   8576 : b0s [128]      permuted, scaled step-0 gate bias
__global__ void precompute_kernel(const float* __restrict__ W_se,
                                  const float* __restrict__ b_se,
                                  const float* __restrict__ W_ih,
                                  const float* __restrict__ b_ih,
                                  const float* __restrict__ W_hh,
                                  const float* __restrict__ b_hh,
                                  const float* __restrict__ W_hp,
                                  const float* __restrict__ b_hp,
                                  float* __restrict__ ws) {
    int s = threadIdx.x;
    if (s >= 128) return;
    int gi = s >> 5, hf = (s >> 4) & 1, q = (s >> 2) & 3, r = s & 3;
    int o  = gi * 32 + 8 * q + 4 * hf + r;          // original gate row
    float w0 = 0.f, w1 = 0.f, bse = 0.f;
    for (int e = 0; e < 32; ++e) {
        float wi = W_ih[o * 32 + e];
        w0  += W_se[e * 2 + 0] * wi;
        w1  += W_se[e * 2 + 1] * wi;
        bse += b_se[e] * wi;
    }
    // i,f,o rows scaled by -log2e (sigmoid via exp2); g rows by 2*log2e (tanh)
    float sc = (gi == 2) ? 2.0f * L2E : -L2E;
    for (int k = 0; k < 32; ++k) {
        float whh = W_hh[o * 32 + k];
        ws[s * 32 + k]        = sc * (whh + W_hp[k] * w0 + W_hp[32 + k] * w1);
        ws[4096 + s * 32 + k] = sc * whh;
    }
    float bg = b_ih[o] + b_hh[o] + bse;
    ws[8192 + s] = sc * w0;
    ws[8320 + s] = sc * w1;
    ws[8448 + s] = sc * (bg + b_hp[0] * w0 + b_hp[1] * w1);
    ws[8576 + s] = sc * bg;
}

// exact hi/lo f16 split of 8 floats
__device__ __forceinline__ void split8(const float* v, half8& hi, half8& lo) {
    #pragma unroll
    for (int p = 0; p < 4; ++p) {
        half2v hp = __builtin_amdgcn_cvt_pkrtz(v[2 * p], v[2 * p + 1]);
        hi[2 * p] = hp.x; hi[2 * p + 1] = hp.y;
        float l0 = v[2 * p]     - (float)hp.x;
        float l1 = v[2 * p + 1] - (float)hp.y;
        half2v lp2 = __builtin_amdgcn_cvt_pkrtz(l0, l1);
        lo[2 * p] = lp2.x; lo[2 * p + 1] = lp2.y;
    }
}

// Single tile per wave, 4 waves/block. Register budget tuned for 4 waves/SIMD
// at __launch_bounds__(256,4): acc-class 68 (accg 32 + wh 32 + ph 4) +
// arch ~55 <= 128. No LDS, no syncs, no fp32 h array (bh f16 fragment only).
__global__ __launch_bounds__(256, 4) void lstm_kernel(
        const float* __restrict__ lp,    // last_pos_rel (B,2)
        const float* __restrict__ h0g,   // hidden_state (1,B,32)
        const float* __restrict__ sp,    // start_pos (B,2)
        const float* __restrict__ Whp,   // (2,32)
        const float* __restrict__ bhp,   // (2)
        const float* __restrict__ ws,
        const int*   __restrict__ seqp,
        float* __restrict__ out, int Bn) {
    const int lane = threadIdx.x & 63;
    const int col  = lane & 15;          // agent within tile
    const int q    = lane >> 4;
    const int base = (blockIdx.x * 4 + (threadIdx.x >> 6)) * 16;
    if (base >= Bn) return;
    const int T = seqp[0];

    const float* Wcs  = ws;
    const float* Whhs = ws + 4096;
    const float* W00s = ws + 8192;
    const float* W01s = ws + 8320;
    const float* bg2q = ws + 8448 + 4 * q;   // per-lane bias base
    const float* b0sq = ws + 8576 + 4 * q;

    // persistent A-fragments: folded weights + pos head (f16 hi)
    half8 wh[8];
    #pragma unroll
    for (int t8 = 0; t8 < 8; ++t8) {
        const float* p = Wcs + (size_t)(t8 * 16 + col) * 32 + 8 * q;
        #pragma unroll
        for (int pp = 0; pp < 4; ++pp) {
            half2v h2 = __builtin_amdgcn_cvt_pkrtz(p[2 * pp], p[2 * pp + 1]);
            wh[t8][2 * pp] = h2.x; wh[t8][2 * pp + 1] = h2.y;
        }
    }
    half8 ph;
    #pragma unroll
    for (int pp = 0; pp < 4; ++pp) {
        float v0 = (col < 2) ? Whp[col * 32 + 8 * q + 2 * pp]     : 0.f;
        float v1 = (col < 2) ? Whp[col * 32 + 8 * q + 2 * pp + 1] : 0.f;
        half2v h2 = __builtin_amdgcn_cvt_pkrtz(v0, v1);
        ph[2 * pp] = h2.x; ph[2 * pp + 1] = h2.y;
    }
    const float pb0 = (q == 0) ? bhp[0] : 0.f;
    const float pb1 = (q == 0) ? bhp[1] : 0.f;

    // ---- step 0 (one-time, full hi/lo precision on fp32 inputs) ----
    f32x4 accg[8];
    {
        half8 b0h, b0l;
        {
            float v[8];
            const float* p = h0g + (size_t)(base + col) * 32 + 8 * q;
            #pragma unroll
            for (int i = 0; i < 8; ++i) v[i] = p[i];
            split8(v, b0h, b0l);
        }
        half8 lph, lpl;
        #pragma unroll
        for (int i = 0; i < 8; ++i) { lph[i] = (_Float16)0.f; lpl[i] = (_Float16)0.f; }
        if (q == 0) {
            float l0 = lp[(size_t)(base + col) * 2 + 0];
            float l1 = lp[(size_t)(base + col) * 2 + 1];
            half2v x = __builtin_amdgcn_cvt_pkrtz(l0, l1);
            lph[0] = x.x; lph[1] = x.y;
            half2v y = __builtin_amdgcn_cvt_pkrtz(l0 - (float)x.x, l1 - (float)x.y);
            lpl[0] = y.x; lpl[1] = y.y;
        }
        #pragma unroll
        for (int t8 = 0; t8 < 8; ++t8) {
            f32x4 a = *(const f32x4*)(b0sq + t8 * 16);
            half8 ah;
            {
                const float* p = Whhs + (size_t)(t8 * 16 + col) * 32 + 8 * q;
                #pragma unroll
                for (int pp = 0; pp < 4; ++pp) {
                    half2v h2 = __builtin_amdgcn_cvt_pkrtz(p[2 * pp], p[2 * pp + 1]);
                    ah[2 * pp] = h2.x; ah[2 * pp + 1] = h2.y;
                }
            }
            a = MFMA(ah, b0h, a); a = MFMA(ah, b0l, a);
            half8 ch;
            #pragma unroll
            for (int i = 0; i < 8; ++i) ch[i] = (_Float16)0.f;
            if (q == 0) {
                half2v y = __builtin_amdgcn_cvt_pkrtz(W00s[t8 * 16 + col],
                                                      W01s[t8 * 16 + col]);
                ch[0] = y.x; ch[1] = y.y;
            }
            a = MFMA(ch, lph, a); a = MFMA(ch, lpl, a);
            accg[t8] = a;
        }
    }

    // per-lane recurrent state: agent=col, hidden j = 8q+i
    f32x2 c2[4];
    #pragma unroll
    for (int i = 0; i < 4; ++i) c2[i] = (f32x2)0.f;
    float run0 = 0.f, run1 = 0.f;
    if (q == 0) {
        run0 = sp[(size_t)(base + col) * 2 + 0];
        run1 = sp[(size_t)(base + col) * 2 + 1];
    }

    half8 bh;                            // h as f16 B-fragment (persists to epilogue)

    #pragma unroll 1
    for (int n = 0; n < T; ++n) {
        // ---- activations: accg[2*gi+hf][r] -> bh (f16), c2 (f32) ----
        #pragma unroll
        for (int hf = 0; hf < 2; ++hf) {
            #pragma unroll
            for (int rp = 0; rp < 2; ++rp) {
                const int idx = 2 * hf + rp;
                f32x2 gI, gF, gG, gO;
                gI.x = accg[0 + hf][2 * rp]; gI.y = accg[0 + hf][2 * rp + 1];
                gF.x = accg[2 + hf][2 * rp]; gF.y = accg[2 + hf][2 * rp + 1];
                gG.x = accg[4 + hf][2 * rp]; gG.y = accg[4 + hf][2 * rp + 1];
                gO.x = accg[6 + hf][2 * rp]; gO.y = accg[6 + hf][2 * rp + 1];
                f32x2 ei, ef, eg, eo;
                ei.x = __builtin_amdgcn_exp2f(gI.x); ei.y = __builtin_amdgcn_exp2f(gI.y);
                ef.x = __builtin_amdgcn_exp2f(gF.x); ef.y = __builtin_amdgcn_exp2f(gF.y);
                eg.x = __builtin_amdgcn_exp2f(gG.x); eg.y = __builtin_amdgcn_exp2f(gG.y);
                eo.x = __builtin_amdgcn_exp2f(gO.x); eo.y = __builtin_amdgcn_exp2f(gO.y);
                f32x2 Df = ef + 1.f;
                f32x2 P  = (ei + 1.f) * (eg + 1.f);
                f32x2 PD = P * Df;
                f32x2 R;
                R.x = __builtin_amdgcn_rcpf(PD.x); R.y = __builtin_amdgcn_rcpf(PD.y);
                f32x2 cn = ((eg - 1.f) * Df + c2[idx] * P) * R;
                c2[idx] = cn;
                f32x2 arg = cn * (2.f * L2E);
                f32x2 ec;
                ec.x = __builtin_amdgcn_exp2f(arg.x); ec.y = __builtin_amdgcn_exp2f(arg.y);
                f32x2 DDo = (ec + 1.f) * (eo + 1.f);
                f32x2 Rs;
                Rs.x = __builtin_amdgcn_rcpf(DDo.x); Rs.y = __builtin_amdgcn_rcpf(DDo.y);
                f32x2 h2 = (ec - 1.f) * Rs;
                half2v hp = __builtin_amdgcn_cvt_pkrtz(h2.x, h2.y);
                bh[2 * idx] = hp.x; bh[2 * idx + 1] = hp.y;
            }
        }

        // ---- pos_n^T = Whp·h^T + bhp (rows 0,1 -> q==0, regs 0,1) ----
        f32x4 ap;
        ap[0] = pb0; ap[1] = pb1; ap[2] = 0.f; ap[3] = 0.f;
        ap = MFMA(ph, bh, ap);

        // ---- gates_{n+1}^T = Wc_perm·h^T + bg2 (bias loaded transiently) ----
        #pragma unroll
        for (int t8 = 0; t8 < 8; ++t8) {
            f32x4 a = *(const f32x4*)(bg2q + t8 * 16);   // L1-hot, 16 B
            accg[t8] = MFMA(wh[t8], bh, a);
        }

        // ---- cumsum + coalesced float2 store (lanes 0..15) ----
        if (q == 0) {
            run0 += ap[0]; run1 += ap[1];
            float2 w2; w2.x = run0; w2.y = run1;
            *(float2*)(out + 2 * ((size_t)n * Bn + base + col)) = w2;
        }
    }

    // ---- final hidden state from the f16 fragment (error ~2.4e-4) ----
    {
        float* p = out + (size_t)T * Bn * 2 + (size_t)(base + col) * 32 + 8 * q;
        float4 v0, v1;
        v0.x = (float)bh[0]; v0.y = (float)bh[1]; v0.z = (float)bh[2]; v0.w = (float)bh[3];
        v1.x = (float)bh[4]; v1.y = (float)bh[5]; v1.z = (float)bh[6]; v1.w = (float)bh[7];
        *(float4*)(p)     = v0;
        *(float4*)(p + 4) = v1;
    }
}

extern "C" void kernel_launch(void* const* d_in, const int* in_sizes, int n_in,
                              void* d_out, int out_size, void* d_ws, size_t ws_size,
                              hipStream_t stream) {
    const float* last_pos_rel = (const float*)d_in[0];
    const float* hidden_state = (const float*)d_in[1];
    const float* start_pos    = (const float*)d_in[2];
    const float* W_se         = (const float*)d_in[3];
    const float* b_se         = (const float*)d_in[4];
    const float* W_ih         = (const float*)d_in[5];
    const float* b_ih         = (const float*)d_in[6];
    const float* W_hh         = (const float*)d_in[7];
    const float* b_hh         = (const float*)d_in[8];
    const float* W_hp         = (const float*)d_in[9];
    const float* b_hp         = (const float*)d_in[10];
    const int*   seq_len      = (const int*)d_in[11];

    float* out = (float*)d_out;
    float* ws  = (float*)d_ws;

    const int Bn = in_sizes[0] / 2;

    hipLaunchKernelGGL(precompute_kernel, dim3(1), dim3(128), 0, stream,
                       W_se, b_se, W_ih, b_ih, W_hh, b_hh, W_hp, b_hp, ws);

    const int ntiles = (Bn + 15) / 16;
    const int nblk   = (ntiles + 3) / 4;
    hipLaunchKernelGGL(lstm_kernel, dim3(nblk), dim3(256), 0, stream,
                       last_pos_rel, hidden_state, start_pos, W_hp, b_hp,
                       ws, seq_len, out, Bn);
}

// Round 10
// 209.369 us; speedup vs baseline: 1.0326x; 1.0171x over previous
//
#include <hip/hip_runtime.h>

typedef _Float16 half8  __attribute__((ext_vector_type(8)));
typedef __fp16   half2v __attribute__((ext_vector_type(2)));   // cvt_pkrtz return type
typedef float    f32x4  __attribute__((ext_vector_type(4)));
typedef float    f32x2  __attribute__((ext_vector_type(2)));

#define L2E 1.44269504088896340736f
#define MFMA(a, b, c) __builtin_amdgcn_mfma_f32_16x16x32_f16((a), (b), (c), 0, 0, 0)

// Row-permuted + pre-scaled weights: D-fragment of gates^T = Wc·h^T lands
// i,f,g,o for (agent=col, j=8q+i) in-lane; activation output is directly the
// next step's B-fragment. slot s: gi=s>>5, hf=(s>>4)&1, q=(s>>2)&3, r=s&3
//   -> orig gate row o = gi*32 + 8q + 4hf + r.
// ws layout (float offsets):
//   0    : Wcs [128][32]  permuted, scaled folded recurrent weights
//   8192 : W00s[128]      permuted, scaled lp0 rank-1 column
//   8320 : W01s[128]      permuted, scaled lp1 rank-1 column
//   8448 : bg2s[128]      permuted, scaled steady-state gate bias
//   8704 : phf [64][4]    per-lane prebuilt f16 pos-head A-fragment (u32 x4)
__global__ void precompute_kernel(const float* __restrict__ W_se,
                                  const float* __restrict__ b_se,
                                  const float* __restrict__ W_ih,
                                  const float* __restrict__ b_ih,
                                  const float* __restrict__ W_hh,
                                  const float* __restrict__ b_hh,
                                  const float* __restrict__ W_hp,
                                  const float* __restrict__ b_hp,
                                  float* __restrict__ ws) {
    int s = threadIdx.x;
    if (s >= 128) return;
    // pos-head fragment table (lanes 0..63)
    if (s < 64) {
        int colp = s & 15, qp = s >> 4;
        unsigned int* dst = (unsigned int*)ws + 8704 + s * 4;
        for (int pp = 0; pp < 4; ++pp) {
            float v0 = (colp < 2) ? W_hp[colp * 32 + 8 * qp + 2 * pp]     : 0.f;
            float v1 = (colp < 2) ? W_hp[colp * 32 + 8 * qp + 2 * pp + 1] : 0.f;
            half2v h2 = __builtin_amdgcn_cvt_pkrtz(v0, v1);
            dst[pp] = __builtin_bit_cast(unsigned int, h2);
        }
    }
    int gi = s >> 5, hf = (s >> 4) & 1, q = (s >> 2) & 3, r = s & 3;
    int o  = gi * 32 + 8 * q + 4 * hf + r;          // original gate row
    float w0 = 0.f, w1 = 0.f, bse = 0.f;
    for (int e = 0; e < 32; ++e) {
        float wi = W_ih[o * 32 + e];
        w0  += W_se[e * 2 + 0] * wi;
        w1  += W_se[e * 2 + 1] * wi;
        bse += b_se[e] * wi;
    }
    // i,f,o rows scaled by -log2e (sigmoid via exp2); g rows by 2*log2e (tanh)
    float sc = (gi == 2) ? 2.0f * L2E : -L2E;
    for (int k = 0; k < 32; ++k) {
        float whh = W_hh[o * 32 + k];
        ws[s * 32 + k] = sc * (whh + W_hp[k] * w0 + W_hp[32 + k] * w1);
    }
    float bg = b_ih[o] + b_hh[o] + bse;
    ws[8192 + s] = sc * w0;
    ws[8320 + s] = sc * w1;
    ws[8448 + s] = sc * (bg + b_hp[0] * w0 + b_hp[1] * w1);
}

// exact hi/lo f16 split of 8 floats
__device__ __forceinline__ void split8(const float* v, half8& hi, half8& lo) {
    #pragma unroll
    for (int p = 0; p < 4; ++p) {
        half2v hp = __builtin_amdgcn_cvt_pkrtz(v[2 * p], v[2 * p + 1]);
        hi[2 * p] = hp.x; hi[2 * p + 1] = hp.y;
        float l0 = v[2 * p]     - (float)hp.x;
        float l1 = v[2 * p + 1] - (float)hp.y;
        half2v lp2 = __builtin_amdgcn_cvt_pkrtz(l0, l1);
        lo[2 * p] = lp2.x; lo[2 * p + 1] = lp2.y;
    }
}

// volatile 16B load of the pos-head fragment (never becomes persistent)
__device__ __forceinline__ half8 load_ph(const float* phbase, int lane) {
    f32x4 t = *(volatile const f32x4*)(phbase + lane * 4);
    return __builtin_bit_cast(half8, t);
}

// Single tile per wave, 4 waves/block. acc-class = accg 32 + wh 32 = 64;
// pos-head fragment reloaded per step (volatile, L1-hot). Step 0 uses the
// correction identity gates_0 = wh*h0 + bg2 + W0 (x) (lp - (Whp*h0 + bhp)),
// which is algebraically exact and reuses the steady-state fragments.
__global__ __launch_bounds__(256, 4) void lstm_kernel(
        const float* __restrict__ lp,    // last_pos_rel (B,2)
        const float* __restrict__ h0g,   // hidden_state (1,B,32)
        const float* __restrict__ sp,    // start_pos (B,2)
        const float* __restrict__ bhp,   // (2)
        const float* __restrict__ ws,
        const int*   __restrict__ seqp,
        float* __restrict__ out, int Bn) {
    const int lane = threadIdx.x & 63;
    const int col  = lane & 15;          // agent within tile
    const int q    = lane >> 4;
    const int base = (blockIdx.x * 4 + (threadIdx.x >> 6)) * 16;
    if (base >= Bn) return;
    const int T = seqp[0];

    const float* Wcs  = ws;
    const float* W00s = ws + 8192;
    const float* W01s = ws + 8320;
    const float* bg2q = ws + 8448 + 4 * q;   // per-lane bias base
    const float* phb  = ws + 8704;           // pos-head fragment table

    // persistent A-fragments: folded weights only (32 acc regs)
    half8 wh[8];
    #pragma unroll
    for (int t8 = 0; t8 < 8; ++t8) {
        const float* p = Wcs + (size_t)(t8 * 16 + col) * 32 + 8 * q;
        #pragma unroll
        for (int pp = 0; pp < 4; ++pp) {
            half2v h2 = __builtin_amdgcn_cvt_pkrtz(p[2 * pp], p[2 * pp + 1]);
            wh[t8][2 * pp] = h2.x; wh[t8][2 * pp + 1] = h2.y;
        }
    }
    const float pb0 = (q == 0) ? bhp[0] : 0.f;
    const float pb1 = (q == 0) ? bhp[1] : 0.f;

    // ---- step 0 via correction identity ----
    f32x4 accg[8];
    {
        half8 b0h, b0l;                  // h0 fragment, exact hi/lo
        {
            float v[8];
            const float* p = h0g + (size_t)(base + col) * 32 + 8 * q;
            #pragma unroll
            for (int i = 0; i < 8; ++i) v[i] = p[i];
            split8(v, b0h, b0l);
        }
        // p~ = Whp*h0 + bhp  (rows 0,1 -> q==0 regs 0,1)
        half8 pht = load_ph(phb, lane);
        f32x4 ap;
        ap[0] = pb0; ap[1] = pb1; ap[2] = 0.f; ap[3] = 0.f;
        ap = MFMA(pht, b0h, ap);
        ap = MFMA(pht, b0l, ap);
        // delta = lp - p~ as f16 B-fragment (k=0,1 live on q==0)
        half8 dh;
        #pragma unroll
        for (int i = 0; i < 8; ++i) dh[i] = (_Float16)0.f;
        if (q == 0) {
            float d0 = lp[(size_t)(base + col) * 2 + 0] - ap[0];
            float d1 = lp[(size_t)(base + col) * 2 + 1] - ap[1];
            half2v x = __builtin_amdgcn_cvt_pkrtz(d0, d1);
            dh[0] = x.x; dh[1] = x.y;
        }
        #pragma unroll
        for (int t8 = 0; t8 < 8; ++t8) {
            f32x4 a = *(const f32x4*)(bg2q + t8 * 16);
            a = MFMA(wh[t8], b0h, a);
            a = MFMA(wh[t8], b0l, a);
            half8 ch;                    // rank-2 correction A-fragment
            #pragma unroll
            for (int i = 0; i < 8; ++i) ch[i] = (_Float16)0.f;
            if (q == 0) {
                half2v y = __builtin_amdgcn_cvt_pkrtz(W00s[t8 * 16 + col],
                                                      W01s[t8 * 16 + col]);
                ch[0] = y.x; ch[1] = y.y;
            }
            a = MFMA(ch, dh, a);
            accg[t8] = a;
        }
    }

    // per-lane recurrent state: agent=col, hidden j = 8q+i
    f32x2 c2[4];
    #pragma unroll
    for (int i = 0; i < 4; ++i) c2[i] = (f32x2)0.f;
    float run0 = 0.f, run1 = 0.f;
    if (q == 0) {
        run0 = sp[(size_t)(base + col) * 2 + 0];
        run1 = sp[(size_t)(base + col) * 2 + 1];
    }

    half8 bh;                            // h as f16 B-fragment (persists to epilogue)

    #pragma unroll 1
    for (int n = 0; n < T; ++n) {
        // pos-head fragment reload (volatile 16B, L1-hot; in flight during act)
        half8 pht = load_ph(phb, lane);

        // ---- activations: accg[2*gi+hf][r] -> bh (f16), c2 (f32) ----
        #pragma unroll
        for (int hf = 0; hf < 2; ++hf) {
            #pragma unroll
            for (int rp = 0; rp < 2; ++rp) {
                const int idx = 2 * hf + rp;
                f32x2 gI, gF, gG, gO;
                gI.x = accg[0 + hf][2 * rp]; gI.y = accg[0 + hf][2 * rp + 1];
                gF.x = accg[2 + hf][2 * rp]; gF.y = accg[2 + hf][2 * rp + 1];
                gG.x = accg[4 + hf][2 * rp]; gG.y = accg[4 + hf][2 * rp + 1];
                gO.x = accg[6 + hf][2 * rp]; gO.y = accg[6 + hf][2 * rp + 1];
                f32x2 ei, ef, eg, eo;
                ei.x = __builtin_amdgcn_exp2f(gI.x); ei.y = __builtin_amdgcn_exp2f(gI.y);
                ef.x = __builtin_amdgcn_exp2f(gF.x); ef.y = __builtin_amdgcn_exp2f(gF.y);
                eg.x = __builtin_amdgcn_exp2f(gG.x); eg.y = __builtin_amdgcn_exp2f(gG.y);
                eo.x = __builtin_amdgcn_exp2f(gO.x); eo.y = __builtin_amdgcn_exp2f(gO.y);
                f32x2 Df = ef + 1.f;
                f32x2 P  = (ei + 1.f) * (eg + 1.f);
                f32x2 PD = P * Df;
                f32x2 R;
                R.x = __builtin_amdgcn_rcpf(PD.x); R.y = __builtin_amdgcn_rcpf(PD.y);
                f32x2 cn = ((eg - 1.f) * Df + c2[idx] * P) * R;
                c2[idx] = cn;
                f32x2 arg = cn * (2.f * L2E);
                f32x2 ec;
                ec.x = __builtin_amdgcn_exp2f(arg.x); ec.y = __builtin_amdgcn_exp2f(arg.y);
                f32x2 DDo = (ec + 1.f) * (eo + 1.f);
                f32x2 Rs;
                Rs.x = __builtin_amdgcn_rcpf(DDo.x); Rs.y = __builtin_amdgcn_rcpf(DDo.y);
                f32x2 h2 = (ec - 1.f) * Rs;
                half2v hp = __builtin_amdgcn_cvt_pkrtz(h2.x, h2.y);
                bh[2 * idx] = hp.x; bh[2 * idx + 1] = hp.y;
            }
        }

        // ---- pos_n^T = Whp*h^T + bhp (rows 0,1 -> q==0, regs 0,1) ----
        f32x4 ap;
        ap[0] = pb0; ap[1] = pb1; ap[2] = 0.f; ap[3] = 0.f;
        ap = MFMA(pht, bh, ap);

        // ---- gates_{n+1}^T = Wc_perm*h^T + bg2 (bias loaded transiently) ----
        #pragma unroll
        for (int t8 = 0; t8 < 8; ++t8) {
            f32x4 a = *(const f32x4*)(bg2q + t8 * 16);   // L1-hot, 16 B
            accg[t8] = MFMA(wh[t8], bh, a);
        }

        // ---- cumsum + coalesced float2 store (lanes 0..15) ----
        if (q == 0) {
            run0 += ap[0]; run1 += ap[1];
            float2 w2; w2.x = run0; w2.y = run1;
            *(float2*)(out + 2 * ((size_t)n * Bn + base + col)) = w2;
        }
    }

    // ---- final hidden state from the f16 fragment (error ~2.4e-4) ----
    {
        float* p = out + (size_t)T * Bn * 2 + (size_t)(base + col) * 32 + 8 * q;
        float4 v0, v1;
        v0.x = (float)bh[0]; v0.y = (float)bh[1]; v0.z = (float)bh[2]; v0.w = (float)bh[3];
        v1.x = (float)bh[4]; v1.y = (float)bh[5]; v1.z = (float)bh[6]; v1.w = (float)bh[7];
        *(float4*)(p)     = v0;
        *(float4*)(p + 4) = v1;
    }
}

extern "C" void kernel_launch(void* const* d_in, const int* in_sizes, int n_in,
                              void* d_out, int out_size, void* d_ws, size_t ws_size,
                              hipStream_t stream) {
    const float* last_pos_rel = (const float*)d_in[0];
    const float* hidden_state = (const float*)d_in[1];
    const float* start_pos    = (const float*)d_in[2];
    const float* W_se         = (const float*)d_in[3];
    const float* b_se         = (const float*)d_in[4];
    const float* W_ih         = (const float*)d_in[5];
    const float* b_ih         = (const float*)d_in[6];
    const float* W_hh         = (const float*)d_in[7];
    const float* b_hh         = (const float*)d_in[8];
    const float* W_hp         = (const float*)d_in[9];
    const float* b_hp         = (const float*)d_in[10];
    const int*   seq_len      = (const int*)d_in[11];

    float* out = (float*)d_out;
    float* ws  = (float*)d_ws;

    const int Bn = in_sizes[0] / 2;

    hipLaunchKernelGGL(precompute_kernel, dim3(1), dim3(128), 0, stream,
                       W_se, b_se, W_ih, b_ih, W_hh, b_hh, W_hp, b_hp, ws);

    const int ntiles = (Bn + 15) / 16;
    const int nblk   = (ntiles + 3) / 4;
    hipLaunchKernelGGL(lstm_kernel, dim3(nblk), dim3(256), 0, stream,
                       last_pos_rel, hidden_state, start_pos, b_hp,
                       ws, seq_len, out, Bn);
}

// Round 11
// 198.614 us; speedup vs baseline: 1.0885x; 1.0542x over previous
//
#include <hip/hip_runtime.h>

typedef _Float16 half8  __attribute__((ext_vector_type(8)));
typedef __fp16   half2v __attribute__((ext_vector_type(2)));   // cvt_pkrtz return type
typedef float    f32x4  __attribute__((ext_vector_type(4)));
typedef float    f32x2  __attribute__((ext_vector_type(2)));

#define L2E 1.44269504088896340736f
#define MFMA(a, b, c) __builtin_amdgcn_mfma_f32_16x16x32_f16((a), (b), (c), 0, 0, 0)

// Row-permuted + pre-scaled weights: D-fragment of gates^T = Wc·h^T lands
// i,f,g,o for (agent=col, j=8q+i) in-lane; activation output is directly the
// next step's B-fragment. slot s: gi=s>>5, hf=(s>>4)&1, q=(s>>2)&3, r=s&3
//   -> orig gate row o = gi*32 + 8q + 4hf + r.
// ws layout (float offsets):
//   0    : Wcs [128][32]  permuted, scaled folded recurrent weights
//   8192 : W00s[128]      permuted, scaled lp0 rank-1 column
//   8320 : W01s[128]      permuted, scaled lp1 rank-1 column
//   8448 : bg2s[128]      permuted, scaled steady-state gate bias
//   8704 : phf [64][4]    per-lane prebuilt f16 pos-head A-fragment (u32 x4)
__global__ void precompute_kernel(const float* __restrict__ W_se,
                                  const float* __restrict__ b_se,
                                  const float* __restrict__ W_ih,
                                  const float* __restrict__ b_ih,
                                  const float* __restrict__ W_hh,
                                  const float* __restrict__ b_hh,
                                  const float* __restrict__ W_hp,
                                  const float* __restrict__ b_hp,
                                  float* __restrict__ ws) {
    int s = threadIdx.x;
    if (s >= 128) return;
    // pos-head fragment table (lanes 0..63)
    if (s < 64) {
        int colp = s & 15, qp = s >> 4;
        unsigned int* dst = (unsigned int*)ws + 8704 + s * 4;
        for (int pp = 0; pp < 4; ++pp) {
            float v0 = (colp < 2) ? W_hp[colp * 32 + 8 * qp + 2 * pp]     : 0.f;
            float v1 = (colp < 2) ? W_hp[colp * 32 + 8 * qp + 2 * pp + 1] : 0.f;
            half2v h2 = __builtin_amdgcn_cvt_pkrtz(v0, v1);
            dst[pp] = __builtin_bit_cast(unsigned int, h2);
        }
    }
    int gi = s >> 5, hf = (s >> 4) & 1, q = (s >> 2) & 3, r = s & 3;
    int o  = gi * 32 + 8 * q + 4 * hf + r;          // original gate row
    float w0 = 0.f, w1 = 0.f, bse = 0.f;
    for (int e = 0; e < 32; ++e) {
        float wi = W_ih[o * 32 + e];
        w0  += W_se[e * 2 + 0] * wi;
        w1  += W_se[e * 2 + 1] * wi;
        bse += b_se[e] * wi;
    }
    // i,f,o rows scaled by -log2e (sigmoid via exp2); g rows by 2*log2e (tanh)
    float sc = (gi == 2) ? 2.0f * L2E : -L2E;
    for (int k = 0; k < 32; ++k) {
        float whh = W_hh[o * 32 + k];
        ws[s * 32 + k] = sc * (whh + W_hp[k] * w0 + W_hp[32 + k] * w1);
    }
    float bg = b_ih[o] + b_hh[o] + bse;
    ws[8192 + s] = sc * w0;
    ws[8320 + s] = sc * w1;
    ws[8448 + s] = sc * (bg + b_hp[0] * w0 + b_hp[1] * w1);
}

// exact hi/lo f16 split of 8 floats
__device__ __forceinline__ void split8(const float* v, half8& hi, half8& lo) {
    #pragma unroll
    for (int p = 0; p < 4; ++p) {
        half2v hp = __builtin_amdgcn_cvt_pkrtz(v[2 * p], v[2 * p + 1]);
        hi[2 * p] = hp.x; hi[2 * p + 1] = hp.y;
        float l0 = v[2 * p]     - (float)hp.x;
        float l1 = v[2 * p + 1] - (float)hp.y;
        half2v lp2 = __builtin_amdgcn_cvt_pkrtz(l0, l1);
        lo[2 * p] = lp2.x; lo[2 * p + 1] = lp2.y;
    }
}

// Single tile per wave, 4 waves/block. Weight fragments live in per-block LDS
// (identical for all waves/blocks: 8 KB), read per step via volatile
// ds_read_b128 so they never become persistent registers. Persistent regs:
// accg 32 + pht 4 + c2 8 + bh 4 + glue ~ 95 total << 128 (256,4 cap).
__global__ __launch_bounds__(256, 4) void lstm_kernel(
        const float* __restrict__ lp,    // last_pos_rel (B,2)
        const float* __restrict__ h0g,   // hidden_state (1,B,32)
        const float* __restrict__ sp,    // start_pos (B,2)
        const float* __restrict__ bhp,   // (2)
        const float* __restrict__ ws,
        const int*   __restrict__ seqp,
        float* __restrict__ out, int Bn) {
    __shared__ f32x4 wh_lds[8][64];      // [t8][lane] f16x8 fragments, 8 KB

    const int tid  = threadIdx.x;
    const int lane = tid & 63;
    const int col  = lane & 15;          // agent within tile
    const int q    = lane >> 4;
    int base = (blockIdx.x * 4 + (tid >> 6)) * 16;
    if (base + 16 > Bn) base = (Bn >= 16) ? (Bn - 16) : 0;   // clamp (no early return: barrier below)
    const int T = seqp[0];

    const float* Wcs  = ws;
    const float* W00s = ws + 8192;
    const float* W01s = ws + 8320;
    const float* bg2q = ws + 8448 + 4 * q;   // per-lane bias base
    const float* phb  = ws + 8704;           // pos-head fragment table

    // ---- build the shared weight-fragment table (wave 0 only) ----
    if (tid < 64) {
        #pragma unroll
        for (int t8 = 0; t8 < 8; ++t8) {
            const float* p = Wcs + (size_t)(t8 * 16 + (tid & 15)) * 32 + 8 * (tid >> 4);
            half8 w;
            #pragma unroll
            for (int pp = 0; pp < 4; ++pp) {
                half2v h2 = __builtin_amdgcn_cvt_pkrtz(p[2 * pp], p[2 * pp + 1]);
                w[2 * pp] = h2.x; w[2 * pp + 1] = h2.y;
            }
            wh_lds[t8][tid] = __builtin_bit_cast(f32x4, w);
        }
    }
    __syncthreads();

    // volatile LDS read: one ds_read_b128, never hoisted to persistent regs
    #define WHT(t8) __builtin_bit_cast(half8, *(volatile const f32x4*)&wh_lds[(t8)][lane])

    // persistent pos-head fragment (4 regs) + bias scalars
    half8 pht = __builtin_bit_cast(half8, *(const f32x4*)(phb + lane * 4));
    const float pb0 = (q == 0) ? bhp[0] : 0.f;
    const float pb1 = (q == 0) ? bhp[1] : 0.f;

    // ---- step 0 via correction identity:
    //      gates_0 = wh*h0 + bg2 + W0 (x) (lp - (Whp*h0 + bhp)) ----
    f32x4 accg[8];
    {
        half8 b0h, b0l;                  // h0 fragment, exact hi/lo
        {
            float v[8];
            const float* p = h0g + (size_t)(base + col) * 32 + 8 * q;
            #pragma unroll
            for (int i = 0; i < 8; ++i) v[i] = p[i];
            split8(v, b0h, b0l);
        }
        f32x4 ap;
        ap[0] = pb0; ap[1] = pb1; ap[2] = 0.f; ap[3] = 0.f;
        ap = MFMA(pht, b0h, ap);
        ap = MFMA(pht, b0l, ap);
        half8 dh;                        // delta = lp - p~  (k=0,1 live on q==0)
        #pragma unroll
        for (int i = 0; i < 8; ++i) dh[i] = (_Float16)0.f;
        if (q == 0) {
            float d0 = lp[(size_t)(base + col) * 2 + 0] - ap[0];
            float d1 = lp[(size_t)(base + col) * 2 + 1] - ap[1];
            half2v x = __builtin_amdgcn_cvt_pkrtz(d0, d1);
            dh[0] = x.x; dh[1] = x.y;
        }
        #pragma unroll
        for (int t8 = 0; t8 < 8; ++t8) {
            f32x4 a = *(const f32x4*)(bg2q + t8 * 16);
            a = MFMA(WHT(t8), b0h, a);
            a = MFMA(WHT(t8), b0l, a);
            half8 ch;                    // rank-2 correction A-fragment
            #pragma unroll
            for (int i = 0; i < 8; ++i) ch[i] = (_Float16)0.f;
            if (q == 0) {
                half2v y = __builtin_amdgcn_cvt_pkrtz(W00s[t8 * 16 + col],
                                                      W01s[t8 * 16 + col]);
                ch[0] = y.x; ch[1] = y.y;
            }
            a = MFMA(ch, dh, a);
            accg[t8] = a;
        }
    }

    // per-lane recurrent state: agent=col, hidden j = 8q+i
    f32x2 c2[4];
    #pragma unroll
    for (int i = 0; i < 4; ++i) c2[i] = (f32x2)0.f;
    float run0 = 0.f, run1 = 0.f;
    if (q == 0) {
        run0 = sp[(size_t)(base + col) * 2 + 0];
        run1 = sp[(size_t)(base + col) * 2 + 1];
    }

    half8 bh;                            // h as f16 B-fragment (persists to epilogue)

    #pragma unroll 1
    for (int n = 0; n < T; ++n) {
        // ---- activations: accg[2*gi+hf][r] -> bh (f16), c2 (f32) ----
        #pragma unroll
        for (int hf = 0; hf < 2; ++hf) {
            #pragma unroll
            for (int rp = 0; rp < 2; ++rp) {
                const int idx = 2 * hf + rp;
                f32x2 gI, gF, gG, gO;
                gI.x = accg[0 + hf][2 * rp]; gI.y = accg[0 + hf][2 * rp + 1];
                gF.x = accg[2 + hf][2 * rp]; gF.y = accg[2 + hf][2 * rp + 1];
                gG.x = accg[4 + hf][2 * rp]; gG.y = accg[4 + hf][2 * rp + 1];
                gO.x = accg[6 + hf][2 * rp]; gO.y = accg[6 + hf][2 * rp + 1];
                f32x2 ei, ef, eg, eo;
                ei.x = __builtin_amdgcn_exp2f(gI.x); ei.y = __builtin_amdgcn_exp2f(gI.y);
                ef.x = __builtin_amdgcn_exp2f(gF.x); ef.y = __builtin_amdgcn_exp2f(gF.y);
                eg.x = __builtin_amdgcn_exp2f(gG.x); eg.y = __builtin_amdgcn_exp2f(gG.y);
                eo.x = __builtin_amdgcn_exp2f(gO.x); eo.y = __builtin_amdgcn_exp2f(gO.y);
                f32x2 Df = ef + 1.f;
                f32x2 P  = (ei + 1.f) * (eg + 1.f);
                f32x2 PD = P * Df;
                f32x2 R;
                R.x = __builtin_amdgcn_rcpf(PD.x); R.y = __builtin_amdgcn_rcpf(PD.y);
                f32x2 cn = ((eg - 1.f) * Df + c2[idx] * P) * R;
                c2[idx] = cn;
                f32x2 arg = cn * (2.f * L2E);
                f32x2 ec;
                ec.x = __builtin_amdgcn_exp2f(arg.x); ec.y = __builtin_amdgcn_exp2f(arg.y);
                f32x2 DDo = (ec + 1.f) * (eo + 1.f);
                f32x2 Rs;
                Rs.x = __builtin_amdgcn_rcpf(DDo.x); Rs.y = __builtin_amdgcn_rcpf(DDo.y);
                f32x2 h2 = (ec - 1.f) * Rs;
                half2v hp = __builtin_amdgcn_cvt_pkrtz(h2.x, h2.y);
                bh[2 * idx] = hp.x; bh[2 * idx + 1] = hp.y;
            }
        }

        // ---- pos_n^T = Whp*h^T + bhp (rows 0,1 -> q==0, regs 0,1) ----
        f32x4 ap;
        ap[0] = pb0; ap[1] = pb1; ap[2] = 0.f; ap[3] = 0.f;
        ap = MFMA(pht, bh, ap);

        // ---- gates_{n+1}^T = Wc_perm*h^T + bg2 (wh streamed from LDS) ----
        #pragma unroll
        for (int t8 = 0; t8 < 8; ++t8) {
            f32x4 a = *(const f32x4*)(bg2q + t8 * 16);   // L1-hot, 16 B
            accg[t8] = MFMA(WHT(t8), bh, a);
        }

        // ---- cumsum + coalesced float2 store (lanes 0..15) ----
        if (q == 0) {
            run0 += ap[0]; run1 += ap[1];
            float2 w2; w2.x = run0; w2.y = run1;
            *(float2*)(out + 2 * ((size_t)n * Bn + base + col)) = w2;
        }
    }

    // ---- final hidden state from the f16 fragment (error ~2.4e-4) ----
    {
        float* p = out + (size_t)T * Bn * 2 + (size_t)(base + col) * 32 + 8 * q;
        float4 v0, v1;
        v0.x = (float)bh[0]; v0.y = (float)bh[1]; v0.z = (float)bh[2]; v0.w = (float)bh[3];
        v1.x = (float)bh[4]; v1.y = (float)bh[5]; v1.z = (float)bh[6]; v1.w = (float)bh[7];
        *(float4*)(p)     = v0;
        *(float4*)(p + 4) = v1;
    }
    #undef WHT
}

extern "C" void kernel_launch(void* const* d_in, const int* in_sizes, int n_in,
                              void* d_out, int out_size, void* d_ws, size_t ws_size,
                              hipStream_t stream) {
    const float* last_pos_rel = (const float*)d_in[0];
    const float* hidden_state = (const float*)d_in[1];
    const float* start_pos    = (const float*)d_in[2];
    const float* W_se         = (const float*)d_in[3];
    const float* b_se         = (const float*)d_in[4];
    const float* W_ih         = (const float*)d_in[5];
    const float* b_ih         = (const float*)d_in[6];
    const float* W_hh         = (const float*)d_in[7];
    const float* b_hh         = (const float*)d_in[8];
    const float* W_hp         = (const float*)d_in[9];
    const float* b_hp         = (const float*)d_in[10];
    const int*   seq_len      = (const int*)d_in[11];

    float* out = (float*)d_out;
    float* ws  = (float*)d_ws;

    const int Bn = in_sizes[0] / 2;

    hipLaunchKernelGGL(precompute_kernel, dim3(1), dim3(128), 0, stream,
                       W_se, b_se, W_ih, b_ih, W_hh, b_hh, W_hp, b_hp, ws);

    const int ntiles = (Bn + 15) / 16;
    const int nblk   = (ntiles + 3) / 4;
    hipLaunchKernelGGL(lstm_kernel, dim3(nblk), dim3(256), 0, stream,
                       last_pos_rel, hidden_state, start_pos, b_hp,
                       ws, seq_len, out, Bn);
}